// Round 2
// baseline (464.967 us; speedup 1.0000x reference)
//
#include <hip/hip_runtime.h>

// Depth rasterization, MI355X.
// Reference pipeline: gather face verts -> rasterize 640x640 zbuf -> clamp 100
// -> linear resize to 128x128.  The resize samples input coord (i+0.5)*5-0.5 =
// 5i+2 (exact integer) => it is exact subsampling at pixel centers (5j+2.5,
// 5i+2.5).  So we rasterize ONLY the 128x128 sampled pixels (25x less work).
//
// All fp32 arithmetic that decides inside/outside or depth must match numpy's
// evaluation bitwise: same op order, no FMA contraction, IEEE division.

#pragma clang fp contract(off)

#define H_OUT 128
#define W_OUT 128
#define NV 778
#define NF 1538
#define NB 4

// Per-(batch,face) record: x0,y0,x1,y1,x2,y2,z0,z1,z2,s,area,pad  (48 B)
#define TRI_STRIDE 12

__global__ __launch_bounds__(256) void prep_kernel(
    const float* __restrict__ verts,   // [NB][NV][3]
    const int* __restrict__ faces,     // [NF][3] (int32 on device)
    float* __restrict__ tris)          // [NB][NF][TRI_STRIDE]
{
    int t = blockIdx.x * 256 + threadIdx.x;
    if (t >= NB * NF) return;
    int b = t / NF;
    int f = t - b * NF;
    int i0 = faces[f * 3 + 0];
    int i1 = faces[f * 3 + 1];
    int i2 = faces[f * 3 + 2];
    const float* vb = verts + (size_t)b * NV * 3;
    float x0 = vb[i0 * 3 + 0], y0 = vb[i0 * 3 + 1], z0 = vb[i0 * 3 + 2];
    float x1 = vb[i1 * 3 + 0], y1 = vb[i1 * 3 + 1], z1 = vb[i1 * 3 + 2];
    float x2 = vb[i2 * 3 + 0], y2 = vb[i2 * 3 + 1], z2 = vb[i2 * 3 + 2];

    // area = _edge(v0, v1, (x2,y2)) -- pixel independent.
    float area = (x1 - x0) * (y2 - y0) - (y1 - y0) * (x2 - x0);
    float s = 0.0f;
    if (fabsf(area) > 1e-12f) s = (area > 0.0f) ? 1.0f : -1.0f;

    float* o = tris + (size_t)t * TRI_STRIDE;
    o[0] = x0; o[1] = y0; o[2] = x1; o[3] = y1; o[4] = x2; o[5] = y2;
    o[6] = z0; o[7] = z1; o[8] = z2; o[9] = s;  o[10] = area; o[11] = 0.0f;
}

__global__ __launch_bounds__(256) void raster_kernel(
    const float* __restrict__ tris,    // [NB][NF][TRI_STRIDE]
    float* __restrict__ out)           // [NB][H_OUT][W_OUT]
{
    int gid = blockIdx.x;              // 256 blocks: 4 batches x 64 tiles
    int b = gid >> 6;
    int pix = (gid & 63) * 256 + threadIdx.x;   // 0..16383 within batch
    int i = pix >> 7;                  // output row
    int j = pix & 127;                 // output col
    // Sampled pixel center in the 640x640 render grid (exact in fp32).
    float px = 5.0f * (float)j + 2.5f;
    float py = 5.0f * (float)i + 2.5f;

    float zmin = 1e10f;                // BG_DEPTH
    const float* tb = tris + (size_t)b * NF * TRI_STRIDE;

    for (int f = 0; f < NF; ++f) {
        const float* o = tb + f * TRI_STRIDE;   // wave-uniform -> s_load
        float x0 = o[0], y0 = o[1];
        float x1 = o[2], y1 = o[3];
        float x2 = o[4], y2 = o[5];
        float z0 = o[6], z1 = o[7], z2 = o[8];
        float s  = o[9], area = o[10];

        // Exactly the reference's edge functions (no FMA, numpy op order).
        float e0 = (x2 - x1) * (py - y1) - (y2 - y1) * (px - x1);
        float e1 = (x0 - x2) * (py - y2) - (y0 - y2) * (px - x2);
        float e2 = (x1 - x0) * (py - y0) - (y1 - y0) * (px - x0);

        bool inside = (e0 * s >= 0.0f) & (e1 * s >= 0.0f) &
                      (e2 * s >= 0.0f) & (s != 0.0f);
        if (inside) {
            // numerator order: (e0*z0 + e1*z1) + e2*z2 ; IEEE fp32 divide.
            float zpix = ((e0 * z0) + (e1 * z1) + (e2 * z2)) / area;
            zmin = fminf(zmin, zpix);
        }
    }

    out[(size_t)b * (H_OUT * W_OUT) + pix] = fminf(zmin, 100.0f);
}

extern "C" void kernel_launch(void* const* d_in, const int* in_sizes, int n_in,
                              void* d_out, int out_size, void* d_ws, size_t ws_size,
                              hipStream_t stream) {
    const float* verts = (const float*)d_in[0];   // [4][778][3] f32
    const int*   faces = (const int*)d_in[1];     // [1538][3] i32
    float* out = (float*)d_out;                   // [4][128][128] f32
    float* tris = (float*)d_ws;                   // NB*NF*12 floats = 295 KB

    int nprep = (NB * NF + 255) / 256;
    prep_kernel<<<nprep, 256, 0, stream>>>(verts, faces, tris);
    raster_kernel<<<256, 256, 0, stream>>>(tris, out);
}

// Round 3
// 147.426 us; speedup vs baseline: 3.1539x; 3.1539x over previous
//
#include <hip/hip_runtime.h>

// Depth rasterization, MI355X — round 3.
// R2 post-mortem: passed, 465us, VALUBusy 16%, Occupancy 11.6% -> latency-bound
// (1 wave/SIMD).  Fix: (a) split faces into 8 chunks, atomicMin(uint) partial
// results into d_out (8 blocks/CU = max occupancy); (b) 16x16 pixel tiles +
// per-face bbox cull (exact: culled faces contribute only BG to the min).
//
// Inside/depth fp32 math stays bit-identical to numpy: contract off, reference
// op order, IEEE division.

#pragma clang fp contract(off)

#define H_OUT 128
#define W_OUT 128
#define NV 778
#define NF 1538
#define NB 4
#define NCHUNK 8
#define CHUNK 193           // ceil(1538/8)
#define BG_BITS 0x501502f9u // __float_as_uint(1e10f)

// Per-(batch,face) record (16 floats, 64B):
// x0,y0,x1,y1,x2,y2,z0,z1,z2,s,area,xmin,xmax,ymin,ymax,pad
#define TRI_STRIDE 16

__global__ __launch_bounds__(256) void prep_kernel(
    const float* __restrict__ verts,   // [NB][NV][3]
    const int* __restrict__ faces,     // [NF][3]
    float* __restrict__ tris,          // [NB][NF][TRI_STRIDE]
    unsigned int* __restrict__ outu)   // [NB*16384] init to BG bits
{
    int t = blockIdx.x * 256 + threadIdx.x;   // grid = 256 blocks -> 65536
    outu[t] = BG_BITS;                         // init full z-buffer
    if (t >= NB * NF) return;
    int b = t / NF;
    int f = t - b * NF;
    int i0 = faces[f * 3 + 0];
    int i1 = faces[f * 3 + 1];
    int i2 = faces[f * 3 + 2];
    const float* vb = verts + (size_t)b * NV * 3;
    float x0 = vb[i0 * 3 + 0], y0 = vb[i0 * 3 + 1], z0 = vb[i0 * 3 + 2];
    float x1 = vb[i1 * 3 + 0], y1 = vb[i1 * 3 + 1], z1 = vb[i1 * 3 + 2];
    float x2 = vb[i2 * 3 + 0], y2 = vb[i2 * 3 + 1], z2 = vb[i2 * 3 + 2];

    float area = (x1 - x0) * (y2 - y0) - (y1 - y0) * (x2 - x0);
    float s = 0.0f;
    if (fabsf(area) > 1e-12f) s = (area > 0.0f) ? 1.0f : -1.0f;

    float xmin = fminf(fminf(x0, x1), x2), xmax = fmaxf(fmaxf(x0, x1), x2);
    float ymin = fminf(fminf(y0, y1), y2), ymax = fmaxf(fmaxf(y0, y1), y2);
    if (s == 0.0f) { xmin = 1e30f; }   // degenerate -> always culled (valid=false)

    float* o = tris + (size_t)t * TRI_STRIDE;
    o[0] = x0;  o[1] = y0;  o[2] = x1;  o[3] = y1;  o[4] = x2;  o[5] = y2;
    o[6] = z0;  o[7] = z1;  o[8] = z2;  o[9] = s;   o[10] = area;
    o[11] = xmin; o[12] = xmax; o[13] = ymin; o[14] = ymax; o[15] = 0.0f;
}

__global__ __launch_bounds__(256) void raster_kernel(
    const float* __restrict__ tris,    // [NB][NF][TRI_STRIDE]
    unsigned int* __restrict__ outu)   // [NB*16384], atomicMin target
{
    int blk = blockIdx.x;              // 2048 = chunk(8) x batch(4) x tile(64)
    int tile  = blk & 63;
    int b     = (blk >> 6) & 3;
    int chunk = blk >> 8;

    int tx = tile & 7, ty = tile >> 3;           // 16x16-pixel tile
    int r  = threadIdx.x >> 4, c = threadIdx.x & 15;
    int i = ty * 16 + r;                          // output row
    int j = tx * 16 + c;                          // output col
    float px = 5.0f * (float)j + 2.5f;            // sampled render-grid center
    float py = 5.0f * (float)i + 2.5f;

    // Tile extent in render coords (for bbox cull).
    float px_lo = 80.0f * (float)tx + 2.5f, px_hi = px_lo + 75.0f;
    float py_lo = 80.0f * (float)ty + 2.5f, py_hi = py_lo + 75.0f;

    float zmin = 1e10f;
    const float* tb = tris + (size_t)b * NF * TRI_STRIDE;
    int f_end = CHUNK * chunk + CHUNK;
    if (f_end > NF) f_end = NF;

    for (int f = CHUNK * chunk; f < f_end; ++f) {
        const float* o = tb + f * TRI_STRIDE;    // wave-uniform
        float xmin = o[11], xmax = o[12], ymin = o[13], ymax = o[14];
        // Conservative exact cull: no pixel of this tile can be inside.
        if (xmin > px_hi || xmax < px_lo || ymin > py_hi || ymax < py_lo)
            continue;

        float x0 = o[0], y0 = o[1];
        float x1 = o[2], y1 = o[3];
        float x2 = o[4], y2 = o[5];
        float z0 = o[6], z1 = o[7], z2 = o[8];
        float s  = o[9], area = o[10];

        // Reference edge functions (no FMA, numpy op order).
        float e0 = (x2 - x1) * (py - y1) - (y2 - y1) * (px - x1);
        float e1 = (x0 - x2) * (py - y2) - (y0 - y2) * (px - x2);
        float e2 = (x1 - x0) * (py - y0) - (y1 - y0) * (px - x0);

        bool inside = (e0 * s >= 0.0f) & (e1 * s >= 0.0f) & (e2 * s >= 0.0f);
        if (inside) {
            float zpix = ((e0 * z0) + (e1 * z1) + (e2 * z2)) / area;
            zpix += 0.0f;                        // -0.0 -> +0.0 (uint order)
            zmin = fminf(zmin, zpix);
        }
    }

    if (zmin < 1e10f)
        atomicMin(&outu[(size_t)b * (H_OUT * W_OUT) + i * W_OUT + j],
                  __float_as_uint(zmin));
}

__global__ __launch_bounds__(256) void finalize_kernel(float* __restrict__ out) {
    int t = blockIdx.x * 256 + threadIdx.x;      // 65536 threads
    out[t] = fminf(out[t], 100.0f);
}

extern "C" void kernel_launch(void* const* d_in, const int* in_sizes, int n_in,
                              void* d_out, int out_size, void* d_ws, size_t ws_size,
                              hipStream_t stream) {
    const float* verts = (const float*)d_in[0];   // [4][778][3] f32
    const int*   faces = (const int*)d_in[1];     // [1538][3] i32
    float* out = (float*)d_out;                   // [4][128][128] f32
    float* tris = (float*)d_ws;                   // 4*1538*16*4B = 384 KB

    prep_kernel<<<256, 256, 0, stream>>>(verts, faces, tris, (unsigned int*)out);
    raster_kernel<<<NCHUNK * NB * 64, 256, 0, stream>>>(tris, (unsigned int*)out);
    finalize_kernel<<<256, 256, 0, stream>>>(out);
}

// Round 4
// 127.493 us; speedup vs baseline: 3.6470x; 1.1563x over previous
//
#include <hip/hip_runtime.h>

// Depth rasterization, MI355X — round 4.
// R3 post-mortem: raster 96us, VALUBusy 34.5%, Occupancy 55.6% -> load
// imbalance (2048 blocks = exact machine fill, no oversubscription; block
// runtimes vary ~5-10x with bbox cull).  VALU-busy floor ~33us.
// Fixes: (a) 32 chunks -> 8192 blocks (4 scheduling rounds amortize tails);
// (b) per-WAVE y-cull (4 rows = 20 render px vs 80) kept fully scalar;
// (c) fold s=+-1 into precomputed edge deltas and area (exact: sign flips
// commute through RN mul/sub/div), deleting 3 muls + 6 subs per survivor.
// Degenerate faces (s=0) -> inverted bbox -> always culled (valid=false).
//
// Inside/depth fp32 math remains bit-identical to numpy: contract off,
// reference op order, IEEE division.

#pragma clang fp contract(off)

#define H_OUT 128
#define W_OUT 128
#define NV 778
#define NF 1538
#define NB 4
#define NCHUNK 32
#define CHUNK 49            // ceil(1538/32)
#define BG 1e10f

// data record (16 floats):
// [0]sdx12 [1]sdy12 [2]sdx02 [3]sdy02 [4]sdx01 [5]sdy01
// [6]x0 [7]y0 [8]x1 [9]y1 [10]x2 [11]y2  [12]z0 [13]z1 [14]z2 [15]sarea

__global__ __launch_bounds__(256) void prep_kernel(
    const float* __restrict__ verts,   // [NB][NV][3]
    const int* __restrict__ faces,     // [NF][3]
    float* __restrict__ bbox,          // [NB*NF][4]
    float* __restrict__ data)          // [NB*NF][16]
{
    int t = blockIdx.x * 256 + threadIdx.x;
    if (t >= NB * NF) return;
    int b = t / NF;
    int f = t - b * NF;
    int i0 = faces[f * 3 + 0];
    int i1 = faces[f * 3 + 1];
    int i2 = faces[f * 3 + 2];
    const float* vb = verts + (size_t)b * NV * 3;
    float x0 = vb[i0 * 3 + 0], y0 = vb[i0 * 3 + 1], z0 = vb[i0 * 3 + 2];
    float x1 = vb[i1 * 3 + 0], y1 = vb[i1 * 3 + 1], z1 = vb[i1 * 3 + 2];
    float x2 = vb[i2 * 3 + 0], y2 = vb[i2 * 3 + 1], z2 = vb[i2 * 3 + 2];

    // Exactly the reference's deltas (each a single RN subtract).
    float dx12 = x2 - x1, dy12 = y2 - y1;
    float dx02 = x0 - x2, dy02 = y0 - y2;
    float dx01 = x1 - x0, dy01 = y1 - y0;
    float y20 = y2 - y0, x20 = x2 - x0;
    float area = dx01 * y20 - dy01 * x20;    // reference op order

    float s = 0.0f;
    if (fabsf(area) > 1e-12f) s = (area > 0.0f) ? 1.0f : -1.0f;

    float xmin = fminf(fminf(x0, x1), x2), xmax = fmaxf(fmaxf(x0, x1), x2);
    float ymin = fminf(fminf(y0, y1), y2), ymax = fmaxf(fmaxf(y0, y1), y2);
    if (s == 0.0f) xmin = 1e30f;             // always culled (valid=false)

    float* bb = bbox + (size_t)t * 4;
    bb[0] = xmin; bb[1] = xmax; bb[2] = ymin; bb[3] = ymax;

    float* o = data + (size_t)t * 16;
    o[0] = s * dx12; o[1] = s * dy12;        // exact sign folds
    o[2] = s * dx02; o[3] = s * dy02;
    o[4] = s * dx01; o[5] = s * dy01;
    o[6] = x0;  o[7] = y0;  o[8] = x1;  o[9] = y1;  o[10] = x2; o[11] = y2;
    o[12] = z0; o[13] = z1; o[14] = z2; o[15] = s * area;   // = |area|
}

__global__ __launch_bounds__(256) void raster_kernel(
    const float* __restrict__ bbox,    // [NB*NF][4]
    const float* __restrict__ data,    // [NB*NF][16]
    unsigned int* __restrict__ outu)   // [NB*16384], pre-init to 0x4F4F4F4F
{
    int blk = blockIdx.x;              // 8192 = chunk(32) x batch(4) x tile(64)
    int tile  = blk & 63;
    int b     = (blk >> 6) & 3;
    int chunk = blk >> 8;

    int tx = tile & 7, ty = tile >> 3;               // 16x16-pixel tile
    int r  = threadIdx.x >> 4, c = threadIdx.x & 15;
    int i = ty * 16 + r;                              // output row
    int j = tx * 16 + c;                              // output col
    float px = 5.0f * (float)j + 2.5f;                // sampled render center
    float py = 5.0f * (float)i + 2.5f;

    // Wave-uniform cull extents (wave w covers rows 4w..4w+3 of the tile).
    int w = __builtin_amdgcn_readfirstlane((int)threadIdx.x) >> 6;
    float px_lo = 80.0f * (float)tx + 2.5f, px_hi = px_lo + 75.0f;
    float py_lo = 80.0f * (float)ty + 20.0f * (float)w + 2.5f;
    float py_hi = py_lo + 15.0f;

    float zmin = BG;
    int base = b * NF;
    int f0 = CHUNK * chunk;
    int f1 = f0 + CHUNK; if (f1 > NF) f1 = NF;

    for (int f = f0; f < f1; ++f) {
        const float* bb = bbox + (size_t)(base + f) * 4;   // wave-uniform
        float xmin = bb[0], xmax = bb[1], ymin = bb[2], ymax = bb[3];
        if (xmin > px_hi || xmax < px_lo || ymin > py_hi || ymax < py_lo)
            continue;                                      // scalar branch

        const float* o = data + (size_t)(base + f) * 16;   // wave-uniform
        // e_i * s, bit-exact (s folded into deltas; reference op order).
        float e0s = o[0] * (py - o[9])  - o[1] * (px - o[8]);
        float e1s = o[2] * (py - o[11]) - o[3] * (px - o[10]);
        float e2s = o[4] * (py - o[7])  - o[5] * (px - o[6]);

        bool inside = (e0s >= 0.0f) & (e1s >= 0.0f) & (e2s >= 0.0f);
        if (inside) {
            // (s*num)/(s*area) == num/area bit-exactly.
            float n = ((e0s * o[12]) + (e1s * o[13])) + (e2s * o[14]);
            float zpix = n / o[15];
            zmin = fminf(zmin, zpix);
        }
    }

    if (zmin < BG)
        atomicMin(&outu[(size_t)b * (H_OUT * W_OUT) + i * W_OUT + j],
                  __float_as_uint(zmin));
}

__global__ __launch_bounds__(256) void finalize_kernel(float* __restrict__ out) {
    int t = blockIdx.x * 256 + threadIdx.x;      // 65536 threads
    out[t] = fminf(out[t], 100.0f);
}

extern "C" void kernel_launch(void* const* d_in, const int* in_sizes, int n_in,
                              void* d_out, int out_size, void* d_ws, size_t ws_size,
                              hipStream_t stream) {
    const float* verts = (const float*)d_in[0];   // [4][778][3] f32
    const int*   faces = (const int*)d_in[1];     // [1538][3] i32
    float* out = (float*)d_out;                   // [4][128][128] f32
    float* bbox = (float*)d_ws;                   // 4*1538*4  floats =  98 KB
    float* data = bbox + (size_t)NB * NF * 4;     // 4*1538*16 floats = 394 KB

    // Init z-buffer: 0x4F4F4F4F = 3.48e9f (positive, > any depth, > 100).
    hipMemsetAsync(out, 0x4F, (size_t)NB * H_OUT * W_OUT * 4, stream);
    prep_kernel<<<(NB * NF + 255) / 256, 256, 0, stream>>>(verts, faces, bbox, data);
    raster_kernel<<<NCHUNK * NB * 64, 256, 0, stream>>>(bbox, data, (unsigned int*)out);
    finalize_kernel<<<256, 256, 0, stream>>>(out);
}

// Round 5
// 97.548 us; speedup vs baseline: 4.7665x; 1.3070x over previous
//
#include <hip/hip_runtime.h>

// Depth rasterization, MI355X — round 5.
// R4 post-mortem: raster 74us but VALUBusy 32% / occ 61% -> each face
// iteration is a dependent load->wait->branch chain (~1360 cyc wall vs ~50 cyc
// VALU); plus ~53us of non-raster dispatch overhead (4 dispatches).
// Fixes:
//  (a) lane-parallel bbox cull: one vector load + __ballot -> 64-bit survivor
//      mask; survivor loop reads face data from LDS (staged once per block,
//      one coalesced round-trip).  No per-face dependent global loads.
//  (b) deferred divide: track (n*, a*) via cross-multiplied min (operands all
//      >=0, products <=3e12; selection slop ~1e-7 rel, winner's n/a is then
//      the bit-exact reference z).  One IEEE divide per pixel-chunk.
//  (c) 2 dispatches: prep inits zbuf to 100.0f bits; raster atomics
//      min(z,100) (clamp commutes with min) -> no memset, no finalize.
// Inside/edge fp32 math bit-identical to numpy (contract off, reference op
// order); s=+-1 sign folds are exact under RN.

#pragma clang fp contract(off)

#define H_OUT 128
#define W_OUT 128
#define NV 778
#define NF 1538
#define NB 4
#define NCHUNK 25
#define NFP (NCHUNK * 64)          // 1600 padded faces per batch
#define BG100 0x42C80000u          // 100.0f bits (uint order == float order >0)

// data record (16 floats / 64B):
// [0]s*dx12 [1]s*dy12 [2]s*dx02 [3]s*dy02 [4]s*dx01 [5]s*dy01
// [6]x0 [7]y0 [8]x1 [9]y1 [10]x2 [11]y2  [12]z0 [13]z1 [14]z2 [15]s*area
// bbox record (4 floats): xmin, xmax, ymin, ymax  (pad: inverted -> culled)

__global__ __launch_bounds__(256) void prep_kernel(
    const float* __restrict__ verts,   // [NB][NV][3]
    const int* __restrict__ faces,     // [NF][3]
    float* __restrict__ bbox,          // [NB*NFP][4]
    float* __restrict__ data,          // [NB*NFP][16]
    unsigned int* __restrict__ outu)   // [NB*16384]
{
    int t = blockIdx.x * 256 + threadIdx.x;   // grid 256 blocks = 65536
    outu[t] = BG100;                           // init z-buffer to 100.0f
    if (t >= NB * NFP) return;
    int b = t / NFP;
    int f = t - b * NFP;
    float* bb = bbox + (size_t)t * 4;
    if (f >= NF) {                             // pad face: always culled
        bb[0] = 1e30f; bb[1] = -1e30f; bb[2] = 1e30f; bb[3] = -1e30f;
        return;
    }
    int i0 = faces[f * 3 + 0];
    int i1 = faces[f * 3 + 1];
    int i2 = faces[f * 3 + 2];
    const float* vb = verts + (size_t)b * NV * 3;
    float x0 = vb[i0 * 3 + 0], y0 = vb[i0 * 3 + 1], z0 = vb[i0 * 3 + 2];
    float x1 = vb[i1 * 3 + 0], y1 = vb[i1 * 3 + 1], z1 = vb[i1 * 3 + 2];
    float x2 = vb[i2 * 3 + 0], y2 = vb[i2 * 3 + 1], z2 = vb[i2 * 3 + 2];

    // Reference deltas (single RN subtracts) and area (reference op order).
    float dx12 = x2 - x1, dy12 = y2 - y1;
    float dx02 = x0 - x2, dy02 = y0 - y2;
    float dx01 = x1 - x0, dy01 = y1 - y0;
    float y20 = y2 - y0, x20 = x2 - x0;
    float area = dx01 * y20 - dy01 * x20;

    float s = 0.0f;
    if (fabsf(area) > 1e-12f) s = (area > 0.0f) ? 1.0f : -1.0f;

    float xmin = fminf(fminf(x0, x1), x2), xmax = fmaxf(fmaxf(x0, x1), x2);
    float ymin = fminf(fminf(y0, y1), y2), ymax = fmaxf(fmaxf(y0, y1), y2);
    if (s == 0.0f) { xmin = 1e30f; xmax = -1e30f; }  // degenerate -> culled

    bb[0] = xmin; bb[1] = xmax; bb[2] = ymin; bb[3] = ymax;

    float* o = data + (size_t)t * 16;
    o[0] = s * dx12; o[1] = s * dy12;        // exact sign folds (s = +-1)
    o[2] = s * dx02; o[3] = s * dy02;
    o[4] = s * dx01; o[5] = s * dy01;
    o[6] = x0;  o[7] = y0;  o[8] = x1;  o[9] = y1;  o[10] = x2; o[11] = y2;
    o[12] = z0; o[13] = z1; o[14] = z2; o[15] = s * area;   // = |area| > 0
}

__global__ __launch_bounds__(256) void raster_kernel(
    const float* __restrict__ bbox,    // [NB*NFP][4]
    const float* __restrict__ data,    // [NB*NFP][16]
    unsigned int* __restrict__ outu)   // [NB*16384], init 100.0f bits
{
    __shared__ float lds[64 * 16];     // this chunk's 64 face records (4 KB)

    int blk = blockIdx.x;              // 6400 = chunk(25) x batch(4) x tile(64)
    int tile  = blk & 63;
    int b     = (blk >> 6) & 3;
    int chunk = blk >> 8;
    int tid = threadIdx.x;

    // Stage chunk face data -> LDS (256 threads x float4 = 4 KB, coalesced).
    int gbase = b * NFP + chunk * 64;  // first face of chunk
    *(float4*)&lds[tid * 4] =
        *(const float4*)&data[(size_t)gbase * 16 + tid * 4];
    __syncthreads();

    int lane = tid & 63;
    int w = __builtin_amdgcn_readfirstlane(tid >> 6);   // wave id, SGPR

    int tx = tile & 7, ty = tile >> 3;               // 16x16-pixel tile
    int i = ty * 16 + (tid >> 4);                     // output row (wave w: 4 rows)
    int j = tx * 16 + (tid & 15);                     // output col
    float px = 5.0f * (float)j + 2.5f;                // sampled render center
    float py = 5.0f * (float)i + 2.5f;

    // Wave-uniform cull extents (wave w covers rows 4w..4w+3 => 20 render px).
    float px_lo = 80.0f * (float)tx + 2.5f, px_hi = px_lo + 75.0f;
    float py_lo = 80.0f * (float)ty + 20.0f * (float)w + 2.5f;
    float py_hi = py_lo + 15.0f;

    // Lane-parallel bbox cull: lane l tests face gbase+l.  One vector load.
    float4 bb = *(const float4*)&bbox[(size_t)(gbase + lane) * 4];
    bool ov = !(bb.x > px_hi || bb.y < px_lo || bb.z > py_hi || bb.w < py_lo);
    unsigned long long mask = __ballot(ov);

    // Survivor loop: wave-uniform mask walk, face data broadcast from LDS.
    float nbest = 1e10f, abest = 1.0f;
    while (mask) {
        int fs = __builtin_ctzll(mask);
        mask &= mask - 1;
        const float* o = &lds[fs * 16];
        // e_i * s, bit-exact (reference op order, s folded in prep).
        float e0s = o[0] * (py - o[9])  - o[1] * (px - o[8]);
        float e1s = o[2] * (py - o[11]) - o[3] * (px - o[10]);
        float e2s = o[4] * (py - o[7])  - o[5] * (px - o[6]);
        bool inside = (e0s >= 0.0f) & (e1s >= 0.0f) & (e2s >= 0.0f);
        // s*num; (s*num)/(s*area) == num/area bit-exactly (done once at end).
        float n = ((e0s * o[12]) + (e1s * o[13])) + (e2s * o[14]);
        float a = o[15];
        // Cross-multiplied min: n/a < nbest/abest  <=>  n*abest < nbest*a
        // (all operands >= 0; products <= ~3e12, fp32-safe).
        bool take = inside & (n * abest < nbest * a);
        nbest = take ? n : nbest;
        abest = take ? a : abest;
    }

    float z = nbest / abest;           // winner: bit-exact reference quotient
    z += 0.0f;                         // -0.0 -> +0.0 for uint ordering
    if (z < 1e9f)                      // no-hit (1e10/1) or absurd z -> bg 100
        atomicMin(&outu[(size_t)b * (H_OUT * W_OUT) + i * W_OUT + j],
                  __float_as_uint(fminf(z, 100.0f)));
}

extern "C" void kernel_launch(void* const* d_in, const int* in_sizes, int n_in,
                              void* d_out, int out_size, void* d_ws, size_t ws_size,
                              hipStream_t stream) {
    const float* verts = (const float*)d_in[0];   // [4][778][3] f32
    const int*   faces = (const int*)d_in[1];     // [1538][3] i32
    float* out = (float*)d_out;                   // [4][128][128] f32
    float* bbox = (float*)d_ws;                   // 4*1600*4  floats = 100 KB
    float* data = bbox + (size_t)NB * NFP * 4;    // 4*1600*16 floats = 400 KB

    prep_kernel<<<256, 256, 0, stream>>>(verts, faces, bbox, data,
                                         (unsigned int*)out);
    raster_kernel<<<NCHUNK * NB * 64, 256, 0, stream>>>(
        bbox, data, (unsigned int*)out);
}

// Round 6
// 97.401 us; speedup vs baseline: 4.7737x; 1.0015x over previous
//
#include <hip/hip_runtime.h>

// Depth rasterization, MI355X — round 6.
// R5 post-mortem: raster 48.9us, VALUBusy 48%, occ 39%.  VALU-busy time
// ~23.5us = compute floor; loss is duty cycle: (a) survivor walk is a serial
// ctz->ds_read->wait->compute chain (1 face in flight/wave); (b) 4-wave blocks
// couple wave exit times -> ramp/drain tail.  Fixed ~49us harness overhead
// (total-raster constant across rounds 2-5) -> only raster is controllable.
// Fixes: 2-way unrolled mask walk (2 faces in flight, 8 ds_read_b128 per
// iter, one wait); 128-thread blocks (2 waves, 16 WG/CU x 2 = 32 waves/CU,
// LDS 4KB x 16 = 64KB).  Math unchanged (bit-exact path preserved).

#pragma clang fp contract(off)

#define H_OUT 128
#define W_OUT 128
#define NV 778
#define NF 1538
#define NB 4
#define NCHUNK 25
#define NFP (NCHUNK * 64)          // 1600 padded faces per batch
#define BG100 0x42C80000u          // 100.0f bits

// data record (16 floats / 64B):
// [0]s*dx12 [1]s*dy12 [2]s*dx02 [3]s*dy02 [4]s*dx01 [5]s*dy01
// [6]x0 [7]y0 [8]x1 [9]y1 [10]x2 [11]y2  [12]z0 [13]z1 [14]z2 [15]s*area
// bbox record (4 floats): xmin, xmax, ymin, ymax  (pad: inverted -> culled)

__global__ __launch_bounds__(256) void prep_kernel(
    const float* __restrict__ verts,   // [NB][NV][3]
    const int* __restrict__ faces,     // [NF][3]
    float* __restrict__ bbox,          // [NB*NFP][4]
    float* __restrict__ data,          // [NB*NFP][16]
    unsigned int* __restrict__ outu)   // [NB*16384]
{
    int t = blockIdx.x * 256 + threadIdx.x;   // grid 256 blocks = 65536
    outu[t] = BG100;                           // init z-buffer to 100.0f
    if (t >= NB * NFP) return;
    int b = t / NFP;
    int f = t - b * NFP;
    float* bb = bbox + (size_t)t * 4;
    if (f >= NF) {                             // pad face: always culled
        bb[0] = 1e30f; bb[1] = -1e30f; bb[2] = 1e30f; bb[3] = -1e30f;
        return;
    }
    int i0 = faces[f * 3 + 0];
    int i1 = faces[f * 3 + 1];
    int i2 = faces[f * 3 + 2];
    const float* vb = verts + (size_t)b * NV * 3;
    float x0 = vb[i0 * 3 + 0], y0 = vb[i0 * 3 + 1], z0 = vb[i0 * 3 + 2];
    float x1 = vb[i1 * 3 + 0], y1 = vb[i1 * 3 + 1], z1 = vb[i1 * 3 + 2];
    float x2 = vb[i2 * 3 + 0], y2 = vb[i2 * 3 + 1], z2 = vb[i2 * 3 + 2];

    // Reference deltas (single RN subtracts) and area (reference op order).
    float dx12 = x2 - x1, dy12 = y2 - y1;
    float dx02 = x0 - x2, dy02 = y0 - y2;
    float dx01 = x1 - x0, dy01 = y1 - y0;
    float y20 = y2 - y0, x20 = x2 - x0;
    float area = dx01 * y20 - dy01 * x20;

    float s = 0.0f;
    if (fabsf(area) > 1e-12f) s = (area > 0.0f) ? 1.0f : -1.0f;

    float xmin = fminf(fminf(x0, x1), x2), xmax = fmaxf(fmaxf(x0, x1), x2);
    float ymin = fminf(fminf(y0, y1), y2), ymax = fmaxf(fmaxf(y0, y1), y2);
    if (s == 0.0f) { xmin = 1e30f; xmax = -1e30f; }  // degenerate -> culled

    bb[0] = xmin; bb[1] = xmax; bb[2] = ymin; bb[3] = ymax;

    float* o = data + (size_t)t * 16;
    o[0] = s * dx12; o[1] = s * dy12;        // exact sign folds (s = +-1)
    o[2] = s * dx02; o[3] = s * dy02;
    o[4] = s * dx01; o[5] = s * dy01;
    o[6] = x0;  o[7] = y0;  o[8] = x1;  o[9] = y1;  o[10] = x2; o[11] = y2;
    o[12] = z0; o[13] = z1; o[14] = z2; o[15] = s * area;   // = |area| > 0
}

__global__ __launch_bounds__(128) void raster_kernel(
    const float* __restrict__ bbox,    // [NB*NFP][4]
    const float* __restrict__ data,    // [NB*NFP][16]
    unsigned int* __restrict__ outu)   // [NB*16384], init 100.0f bits
{
    __shared__ float lds[64 * 16];     // chunk's 64 face records (4 KB)

    int blk = blockIdx.x;              // 12800 = chunk(25) x batch(4) x tile(128)
    int tile  = blk & 127;             // 16x8-pixel tiles: 8 across, 16 down
    int b     = (blk >> 7) & 3;
    int chunk = blk >> 9;
    int tid = threadIdx.x;             // 128 threads = 2 waves

    // Stage chunk face data -> LDS (128 threads x 2 float4 = 4 KB, coalesced).
    int gbase = b * NFP + chunk * 64;
    const float4* src = (const float4*)&data[(size_t)gbase * 16];
    ((float4*)lds)[tid]       = src[tid];
    ((float4*)lds)[tid + 128] = src[tid + 128];
    __syncthreads();

    int lane = tid & 63;
    int w = __builtin_amdgcn_readfirstlane(tid >> 6);   // wave id 0/1

    int tx = tile & 7, ty = tile >> 3;
    int i = ty * 8 + w * 4 + (lane >> 4);   // output row (wave: 4 rows)
    int j = tx * 16 + (lane & 15);          // output col
    float px = 5.0f * (float)j + 2.5f;
    float py = 5.0f * (float)i + 2.5f;

    // Wave-uniform cull extents (wave covers 4 rows = 15 render px span).
    float px_lo = 80.0f * (float)tx + 2.5f, px_hi = px_lo + 75.0f;
    float py_lo = 40.0f * (float)ty + 20.0f * (float)w + 2.5f;
    float py_hi = py_lo + 15.0f;

    // Lane-parallel bbox cull -> 64-bit survivor mask.
    float4 bb = *(const float4*)&bbox[(size_t)(gbase + lane) * 4];
    bool ov = !(bb.x > px_hi || bb.y < px_lo || bb.z > py_hi || bb.w < py_lo);
    unsigned long long mask = __ballot(ov);

    // Survivor walk, 2 faces per iteration (odd count duplicates the last
    // face: idempotent under strict-< min).  8 ds_read_b128 issue together.
    float nb = 1e10f, ab = 1.0f;
    while (mask) {
        int f0 = __builtin_ctzll(mask); mask &= mask - 1;
        int f1 = mask ? __builtin_ctzll(mask) : f0;
        mask &= mask - 1;

        const float4* p0 = (const float4*)&lds[f0 * 16];
        const float4* p1 = (const float4*)&lds[f1 * 16];
        float4 A0 = p0[0], B0 = p0[1], C0 = p0[2], D0 = p0[3];
        float4 A1 = p1[0], B1 = p1[1], C1 = p1[2], D1 = p1[3];

        // face 0 (bit-exact reference op order; s folded in prep)
        float e0 = A0.x * (py - C0.y) - A0.y * (px - C0.x);
        float e1 = A0.z * (py - C0.w) - A0.w * (px - C0.z);
        float e2 = B0.x * (py - B0.w) - B0.y * (px - B0.z);
        bool in0 = (e0 >= 0.0f) & (e1 >= 0.0f) & (e2 >= 0.0f);
        float n0 = ((e0 * D0.x) + (e1 * D0.y)) + (e2 * D0.z);
        bool t0 = in0 & (n0 * ab < nb * D0.w);
        nb = t0 ? n0 : nb;  ab = t0 ? D0.w : ab;

        // face 1
        float g0 = A1.x * (py - C1.y) - A1.y * (px - C1.x);
        float g1 = A1.z * (py - C1.w) - A1.w * (px - C1.z);
        float g2 = B1.x * (py - B1.w) - B1.y * (px - B1.z);
        bool in1 = (g0 >= 0.0f) & (g1 >= 0.0f) & (g2 >= 0.0f);
        float n1 = ((g0 * D1.x) + (g1 * D1.y)) + (g2 * D1.z);
        bool t1 = in1 & (n1 * ab < nb * D1.w);
        nb = t1 ? n1 : nb;  ab = t1 ? D1.w : ab;
    }

    float z = nb / ab;                 // winner: bit-exact reference quotient
    z += 0.0f;                         // -0.0 -> +0.0 for uint ordering
    if (z < 1e9f)                      // no-hit sentinel (1e10) -> keep bg 100
        atomicMin(&outu[(size_t)b * (H_OUT * W_OUT) + i * W_OUT + j],
                  __float_as_uint(fminf(z, 100.0f)));
}

extern "C" void kernel_launch(void* const* d_in, const int* in_sizes, int n_in,
                              void* d_out, int out_size, void* d_ws, size_t ws_size,
                              hipStream_t stream) {
    const float* verts = (const float*)d_in[0];   // [4][778][3] f32
    const int*   faces = (const int*)d_in[1];     // [1538][3] i32
    float* out = (float*)d_out;                   // [4][128][128] f32
    float* bbox = (float*)d_ws;                   // 4*1600*4  floats = 100 KB
    float* data = bbox + (size_t)NB * NFP * 4;    // 4*1600*16 floats = 400 KB

    prep_kernel<<<256, 256, 0, stream>>>(verts, faces, bbox, data,
                                         (unsigned int*)out);
    raster_kernel<<<NCHUNK * NB * 128, 128, 0, stream>>>(
        bbox, data, (unsigned int*)out);
}